// Round 1
// baseline (1612.703 us; speedup 1.0000x reference)
//
#include <hip/hip_runtime.h>
#include <math.h>

#define NN 100000

// ---------------------------------------------------------------------------
// transform: y[n, :] = h[n, :] @ W   (W is D_IN x D_OUT, row-major)
// ---------------------------------------------------------------------------
template <int D_IN, int D_OUT>
__global__ void transform_kernel(const float* __restrict__ h,
                                 const float* __restrict__ W,
                                 float* __restrict__ y, int n_nodes) {
    constexpr int NPB = 256 / D_OUT;  // nodes per block
    __shared__ float sW[D_IN * D_OUT];
    __shared__ float sh[NPB * D_IN];
    const int t = threadIdx.x;
    for (int i = t; i < D_IN * D_OUT; i += 256) sW[i] = W[i];
    const int node0 = blockIdx.x * NPB;
    for (int i = t; i < NPB * D_IN; i += 256) {
        const int ln = i / D_IN, k = i % D_IN;
        const int n = node0 + ln;
        sh[i] = (n < n_nodes) ? h[(long long)n * D_IN + k] : 0.f;
    }
    __syncthreads();
    const int ln = t / D_OUT, j = t % D_OUT;
    const int n = node0 + ln;
    if (n < n_nodes) {
        float acc = 0.f;
#pragma unroll
        for (int k = 0; k < D_IN; ++k) acc += sh[ln * D_IN + k] * sW[k * D_OUT + j];
        y[(long long)n * D_OUT + j] = acc;
    }
}

// ---------------------------------------------------------------------------
// count: cnt[dst[e]] += 1
// ---------------------------------------------------------------------------
__global__ void count_kernel(const int* __restrict__ dst, float* __restrict__ cnt,
                             int n_edges) {
    const int e = blockIdx.x * 256 + threadIdx.x;
    if (e < n_edges) atomicAdd(&cnt[dst[e]], 1.0f);
}

// ---------------------------------------------------------------------------
// scatter: agg[dst[e], f] += y[src[e], f]  — one thread per (edge, feature)
// ---------------------------------------------------------------------------
template <int D>
__global__ void scatter_kernel(const float* __restrict__ y,
                               const int* __restrict__ src,
                               const int* __restrict__ dst,
                               float* __restrict__ agg, long long total) {
    const long long idx = (long long)blockIdx.x * 256 + threadIdx.x;
    if (idx >= total) return;
    const int e = (int)(idx / D);
    const int f = (int)(idx % D);
    const int s = src[e];
    const int d = dst[e];
    atomicAdd(&agg[(long long)d * D + f], y[(long long)s * D + f]);
}

// ---------------------------------------------------------------------------
// finalize: out[n,j] = act( agg[n,j]/max(cnt[n],1) + b[j] + h[n,:]@Wr[:,j] )
// ACT: 0 = relu, 1 = sigmoid
// ---------------------------------------------------------------------------
template <int D_IN, int D_OUT, int ACT>
__global__ void finalize_kernel(const float* __restrict__ h,
                                const float* __restrict__ W,
                                const float* __restrict__ b,
                                const float* __restrict__ agg,
                                const float* __restrict__ cnt,
                                float* __restrict__ out, int n_nodes) {
    constexpr int NPB = 256 / D_OUT;
    __shared__ float sW[D_IN * D_OUT];
    __shared__ float sh[NPB * D_IN];
    const int t = threadIdx.x;
    for (int i = t; i < D_IN * D_OUT; i += 256) sW[i] = W[i];
    const int node0 = blockIdx.x * NPB;
    for (int i = t; i < NPB * D_IN; i += 256) {
        const int ln = i / D_IN, k = i % D_IN;
        const int n = node0 + ln;
        sh[i] = (n < n_nodes) ? h[(long long)n * D_IN + k] : 0.f;
    }
    __syncthreads();
    const int ln = t / D_OUT, j = t % D_OUT;
    const int n = node0 + ln;
    if (n < n_nodes) {
        float acc = 0.f;
#pragma unroll
        for (int k = 0; k < D_IN; ++k) acc += sh[ln * D_IN + k] * sW[k * D_OUT + j];
        const float c = cnt[n];
        const float mean = agg[(long long)n * D_OUT + j] / fmaxf(c, 1.0f);
        acc += mean + b[j];
        if (ACT == 0) {
            acc = fmaxf(acc, 0.0f);
        } else {
            acc = 1.0f / (1.0f + expf(-acc));
        }
        out[(long long)n * D_OUT + j] = acc;
    }
}

extern "C" void kernel_launch(void* const* d_in, const int* in_sizes, int n_in,
                              void* d_out, int out_size, void* d_ws, size_t ws_size,
                              hipStream_t stream) {
    const float* x = (const float*)d_in[0];
    const int* edge_index = (const int*)d_in[1];
    const float* W1l = (const float*)d_in[2];
    const float* b1  = (const float*)d_in[3];
    const float* W1r = (const float*)d_in[4];
    const float* W2l = (const float*)d_in[5];
    const float* b2  = (const float*)d_in[6];
    const float* W2r = (const float*)d_in[7];
    const float* W3l = (const float*)d_in[8];
    const float* b3  = (const float*)d_in[9];
    const float* W3r = (const float*)d_in[10];
    float* out = (float*)d_out;

    const int E = in_sizes[1] / 2;
    const int* src = edge_index;
    const int* dst = edge_index + E;

    // workspace layout (floats): cnt[N] | y[64N] | agg[64N] | h1[64N] | h2[32N]
    float* w    = (float*)d_ws;
    float* cnt  = w;
    float* y    = cnt + NN;
    float* agg  = y + 64LL * NN;
    float* h1   = agg + 64LL * NN;
    float* h2   = h1 + 64LL * NN;

    const int eb = (E + 255) / 256;

    // shared count (same dst for all layers)
    hipMemsetAsync(cnt, 0, NN * sizeof(float), stream);
    count_kernel<<<eb, 256, 0, stream>>>(dst, cnt, E);

    // ---- layer 1: 64 -> 64, relu ----
    hipMemsetAsync(agg, 0, 64LL * NN * sizeof(float), stream);
    transform_kernel<64, 64><<<(NN + 3) / 4, 256, 0, stream>>>(x, W1l, y, NN);
    {
        const long long total = (long long)E * 64;
        scatter_kernel<64><<<(int)((total + 255) / 256), 256, 0, stream>>>(y, src, dst, agg, total);
    }
    finalize_kernel<64, 64, 0><<<(NN + 3) / 4, 256, 0, stream>>>(x, W1r, b1, agg, cnt, h1, NN);

    // ---- layer 2: 64 -> 32, relu ----
    hipMemsetAsync(agg, 0, 32LL * NN * sizeof(float), stream);
    transform_kernel<64, 32><<<(NN + 7) / 8, 256, 0, stream>>>(h1, W2l, y, NN);
    {
        const long long total = (long long)E * 32;
        scatter_kernel<32><<<(int)((total + 255) / 256), 256, 0, stream>>>(y, src, dst, agg, total);
    }
    finalize_kernel<64, 32, 0><<<(NN + 7) / 8, 256, 0, stream>>>(h1, W2r, b2, agg, cnt, h2, NN);

    // ---- layer 3: 32 -> 1, sigmoid ----
    hipMemsetAsync(agg, 0, NN * sizeof(float), stream);
    transform_kernel<32, 1><<<(NN + 255) / 256, 256, 0, stream>>>(h2, W3l, y, NN);
    {
        const long long total = (long long)E;
        scatter_kernel<1><<<(int)((total + 255) / 256), 256, 0, stream>>>(y, src, dst, agg, total);
    }
    finalize_kernel<32, 1, 1><<<(NN + 255) / 256, 256, 0, stream>>>(h2, W3r, b3, agg, cnt, out, NN);
}

// Round 2
// 860.443 us; speedup vs baseline: 1.8743x; 1.8743x over previous
//
#include <hip/hip_runtime.h>
#include <math.h>

#define NN 100000

// ---------------------------------------------------------------------------
// transform: y[n, :] = h[n, :] @ W   (W is D_IN x D_OUT, row-major)
// ---------------------------------------------------------------------------
template <int D_IN, int D_OUT>
__global__ void transform_kernel(const float* __restrict__ h,
                                 const float* __restrict__ W,
                                 float* __restrict__ y, int n_nodes) {
    constexpr int NPB = 256 / D_OUT;                 // nodes per block
    constexpr int STR = D_IN + (D_OUT == 1 ? 1 : 0); // pad when lanes stride rows
    __shared__ float sW[D_IN * D_OUT];
    __shared__ float sh[NPB * STR];
    const int t = threadIdx.x;
    for (int i = t; i < D_IN * D_OUT; i += 256) sW[i] = W[i];
    const int node0 = blockIdx.x * NPB;
    for (int i = t; i < NPB * D_IN; i += 256) {
        const int ln = i / D_IN, k = i % D_IN;
        const int n = node0 + ln;
        sh[ln * STR + k] = (n < n_nodes) ? h[(long long)n * D_IN + k] : 0.f;
    }
    __syncthreads();
    const int ln = t / D_OUT, j = t % D_OUT;
    const int n = node0 + ln;
    if (n < n_nodes) {
        float acc = 0.f;
#pragma unroll
        for (int k = 0; k < D_IN; ++k) acc += sh[ln * STR + k] * sW[k * D_OUT + j];
        y[(long long)n * D_OUT + j] = acc;
    }
}

// ---------------------------------------------------------------------------
// CSR build: histogram -> 2-level exclusive scan -> placement
// ---------------------------------------------------------------------------
__global__ void hist_kernel(const int* __restrict__ dst, int* __restrict__ hist,
                            int n_edges) {
    const int e = blockIdx.x * 256 + threadIdx.x;
    if (e < n_edges) atomicAdd(&hist[dst[e]], 1);
}

// block b sums hist[b*1024 .. b*1024+1024)
__global__ void reduce_chunk_kernel(const int* __restrict__ hist,
                                    int* __restrict__ partial, int n) {
    __shared__ int sdata[256];
    const int base = blockIdx.x * 1024;
    int sum = 0;
    for (int i = threadIdx.x; i < 1024; i += 256) {
        const int idx = base + i;
        sum += (idx < n) ? hist[idx] : 0;
    }
    sdata[threadIdx.x] = sum;
    __syncthreads();
    for (int off = 128; off > 0; off >>= 1) {
        if (threadIdx.x < off) sdata[threadIdx.x] += sdata[threadIdx.x + off];
        __syncthreads();
    }
    if (threadIdx.x == 0) partial[blockIdx.x] = sdata[0];
}

// single block: exclusive-scan partials in place, write grand total
__global__ void scan_partials_kernel(int* __restrict__ partial, int nb,
                                     int* __restrict__ total_out) {
    __shared__ int s[128];
    const int t = threadIdx.x;
    const int v = (t < nb) ? partial[t] : 0;
    s[t] = v;
    __syncthreads();
    for (int off = 1; off < 128; off <<= 1) {
        const int tmp = (t >= off) ? s[t - off] : 0;
        __syncthreads();
        s[t] += tmp;
        __syncthreads();
    }
    if (t < nb) partial[t] = s[t] - v;  // exclusive
    if (t == 127) *total_out = s[127];
}

__global__ void __launch_bounds__(1024)
scan_chunk_kernel(const int* __restrict__ hist, const int* __restrict__ partial,
                  int* __restrict__ row_ptr, int* __restrict__ cursor, int n) {
    __shared__ int s[1024];
    const int t = threadIdx.x;
    const int idx = blockIdx.x * 1024 + t;
    const int v = (idx < n) ? hist[idx] : 0;
    s[t] = v;
    __syncthreads();
    for (int off = 1; off < 1024; off <<= 1) {
        const int tmp = (t >= off) ? s[t - off] : 0;
        __syncthreads();
        s[t] += tmp;
        __syncthreads();
    }
    if (idx < n) {
        const int ex = partial[blockIdx.x] + s[t] - v;
        row_ptr[idx] = ex;
        cursor[idx] = ex;
    }
}

__global__ void place_kernel(const int* __restrict__ src, const int* __restrict__ dst,
                             int* __restrict__ cursor, int* __restrict__ ssrc,
                             int n_edges) {
    const int e = blockIdx.x * 256 + threadIdx.x;
    if (e < n_edges) {
        const int p = atomicAdd(&cursor[dst[e]], 1);
        ssrc[p] = src[e];
    }
}

// ---------------------------------------------------------------------------
// gather-side mean aggregation: mean[n,:] = (1/max(deg,1)) * sum y[ssrc[e],:]
// one group of D threads per node; lane holds one feature
// ---------------------------------------------------------------------------
template <int D>
__global__ void agg_mean_kernel(const float* __restrict__ y,
                                const int* __restrict__ row_ptr,
                                const int* __restrict__ ssrc,
                                float* __restrict__ mean, int n_nodes) {
    constexpr int NPB = 256 / D;
    const int g = threadIdx.x / D;
    const int lane = threadIdx.x % D;
    const int n = blockIdx.x * NPB + g;
    if (n >= n_nodes) return;
    const int s0 = row_ptr[n], s1 = row_ptr[n + 1];
    float acc = 0.f;
    int e = s0;
    for (; e + 4 <= s1; e += 4) {
        const int a = ssrc[e], b = ssrc[e + 1], c = ssrc[e + 2], d = ssrc[e + 3];
        const float v0 = y[(long long)a * D + lane];
        const float v1 = y[(long long)b * D + lane];
        const float v2 = y[(long long)c * D + lane];
        const float v3 = y[(long long)d * D + lane];
        acc += v0 + v1 + v2 + v3;
    }
    for (; e < s1; ++e) acc += y[(long long)ssrc[e] * D + lane];
    const int deg = s1 - s0;
    mean[(long long)n * D + lane] = acc / (float)((deg > 0) ? deg : 1);
}

// ---------------------------------------------------------------------------
// finalize: out[n,j] = act( mean[n,j] + b[j] + h[n,:]@Wr[:,j] )
// ACT: 0 = relu, 1 = sigmoid
// ---------------------------------------------------------------------------
template <int D_IN, int D_OUT, int ACT>
__global__ void finalize_kernel(const float* __restrict__ h,
                                const float* __restrict__ W,
                                const float* __restrict__ b,
                                const float* __restrict__ mean,
                                float* __restrict__ out, int n_nodes) {
    constexpr int NPB = 256 / D_OUT;
    constexpr int STR = D_IN + (D_OUT == 1 ? 1 : 0);
    __shared__ float sW[D_IN * D_OUT];
    __shared__ float sh[NPB * STR];
    const int t = threadIdx.x;
    for (int i = t; i < D_IN * D_OUT; i += 256) sW[i] = W[i];
    const int node0 = blockIdx.x * NPB;
    for (int i = t; i < NPB * D_IN; i += 256) {
        const int ln = i / D_IN, k = i % D_IN;
        const int n = node0 + ln;
        sh[ln * STR + k] = (n < n_nodes) ? h[(long long)n * D_IN + k] : 0.f;
    }
    __syncthreads();
    const int ln = t / D_OUT, j = t % D_OUT;
    const int n = node0 + ln;
    if (n < n_nodes) {
        float acc = 0.f;
#pragma unroll
        for (int k = 0; k < D_IN; ++k) acc += sh[ln * STR + k] * sW[k * D_OUT + j];
        acc += mean[(long long)n * D_OUT + j] + b[j];
        if (ACT == 0) {
            acc = fmaxf(acc, 0.0f);
        } else {
            acc = 1.0f / (1.0f + expf(-acc));
        }
        out[(long long)n * D_OUT + j] = acc;
    }
}

extern "C" void kernel_launch(void* const* d_in, const int* in_sizes, int n_in,
                              void* d_out, int out_size, void* d_ws, size_t ws_size,
                              hipStream_t stream) {
    const float* x = (const float*)d_in[0];
    const int* edge_index = (const int*)d_in[1];
    const float* W1l = (const float*)d_in[2];
    const float* b1  = (const float*)d_in[3];
    const float* W1r = (const float*)d_in[4];
    const float* W2l = (const float*)d_in[5];
    const float* b2  = (const float*)d_in[6];
    const float* W2r = (const float*)d_in[7];
    const float* W3l = (const float*)d_in[8];
    const float* b3  = (const float*)d_in[9];
    const float* W3r = (const float*)d_in[10];
    float* out = (float*)d_out;

    const int E = in_sizes[1] / 2;
    const int* src = edge_index;
    const int* dst = edge_index + E;

    // workspace layout: floats bufY[64N] | bufM[64N] | h1[64N] | h2[32N]
    // then ints: hist[N] | row_ptr[N+1] | cursor[N] | partial[128] | ssrc[E]
    float* bufY = (float*)d_ws;
    float* bufM = bufY + 64LL * NN;
    float* h1   = bufM + 64LL * NN;
    float* h2   = h1 + 64LL * NN;
    int* ibase   = (int*)(h2 + 32LL * NN);
    int* hist    = ibase;
    int* row_ptr = hist + NN;
    int* cursor  = row_ptr + NN + 1;
    int* partial = cursor + NN;
    int* ssrc    = partial + 128;

    const int eb = (E + 255) / 256;
    const int nchunks = (NN + 1023) / 1024;  // 98

    // ---- CSR build (dst identical across all 3 layers) ----
    hipMemsetAsync(hist, 0, NN * sizeof(int), stream);
    hist_kernel<<<eb, 256, 0, stream>>>(dst, hist, E);
    reduce_chunk_kernel<<<nchunks, 256, 0, stream>>>(hist, partial, NN);
    scan_partials_kernel<<<1, 128, 0, stream>>>(partial, nchunks, &row_ptr[NN]);
    scan_chunk_kernel<<<nchunks, 1024, 0, stream>>>(hist, partial, row_ptr, cursor, NN);
    place_kernel<<<eb, 256, 0, stream>>>(src, dst, cursor, ssrc, E);

    // ---- layer 1: 64 -> 64, relu ----
    transform_kernel<64, 64><<<(NN + 3) / 4, 256, 0, stream>>>(x, W1l, bufY, NN);
    agg_mean_kernel<64><<<(NN + 3) / 4, 256, 0, stream>>>(bufY, row_ptr, ssrc, bufM, NN);
    finalize_kernel<64, 64, 0><<<(NN + 3) / 4, 256, 0, stream>>>(x, W1r, b1, bufM, h1, NN);

    // ---- layer 2: 64 -> 32, relu ----
    transform_kernel<64, 32><<<(NN + 7) / 8, 256, 0, stream>>>(h1, W2l, bufY, NN);
    agg_mean_kernel<32><<<(NN + 7) / 8, 256, 0, stream>>>(bufY, row_ptr, ssrc, bufM, NN);
    finalize_kernel<64, 32, 0><<<(NN + 7) / 8, 256, 0, stream>>>(h1, W2r, b2, bufM, h2, NN);

    // ---- layer 3: 32 -> 1, sigmoid ----
    transform_kernel<32, 1><<<(NN + 255) / 256, 256, 0, stream>>>(h2, W3l, bufY, NN);
    agg_mean_kernel<1><<<(NN + 255) / 256, 256, 0, stream>>>(bufY, row_ptr, ssrc, bufM, NN);
    finalize_kernel<32, 1, 1><<<(NN + 255) / 256, 256, 0, stream>>>(h2, W3r, b3, bufM, out, NN);
}